// Round 7
// baseline (935.016 us; speedup 1.0000x reference)
//
#include <hip/hip_runtime.h>
#include <math.h>

#define B_ 128
#define T_ 1024
#define H_ 256
#define Z_ 64
#define M_ (B_ * T_)   // 131072 rows

typedef _Float16 h2 __attribute__((ext_vector_type(2)));
typedef _Float16 h4 __attribute__((ext_vector_type(4)));

// ---------------------------------------------------------------------------
// Kernel 1: precompute the non-recurrent part of both matmuls (unchanged).
// ---------------------------------------------------------------------------
__global__ __launch_bounds__(256) void precompute_kernel(
    const float* __restrict__ Hm,    // [M_, 256]
    const float* __restrict__ Wmu,   // [64, 320]
    const float* __restrict__ Wstd,  // [64, 320]
    const float* __restrict__ bmu,   // [64]
    const float* __restrict__ bstd,  // [64]
    float* __restrict__ pre_mu,      // [M_, 64]
    float* __restrict__ pre_std)     // [M_, 64]
{
    const int tid = threadIdx.x;
    const int ty = tid >> 4;
    const int tx = tid & 15;
    const int m0 = blockIdx.x * 64;

    __shared__ float Ash[64][17];
    __shared__ float Wm[64][17];
    __shared__ float Ws[64][17];

    float accm[4][4] = {};
    float accs[4][4] = {};

    const int lrow = tid >> 2;
    const int lk   = (tid & 3) * 4;

    for (int k0 = 0; k0 < 256; k0 += 16) {
        float4 av  = *reinterpret_cast<const float4*>(&Hm[(size_t)(m0 + lrow) * H_ + k0 + lk]);
        float4 wmv = *reinterpret_cast<const float4*>(&Wmu[(size_t)lrow * 320 + k0 + lk]);
        float4 wsv = *reinterpret_cast<const float4*>(&Wstd[(size_t)lrow * 320 + k0 + lk]);
        __syncthreads();
        Ash[lrow][lk + 0] = av.x;  Ash[lrow][lk + 1] = av.y;
        Ash[lrow][lk + 2] = av.z;  Ash[lrow][lk + 3] = av.w;
        Wm[lrow][lk + 0] = wmv.x;  Wm[lrow][lk + 1] = wmv.y;
        Wm[lrow][lk + 2] = wmv.z;  Wm[lrow][lk + 3] = wmv.w;
        Ws[lrow][lk + 0] = wsv.x;  Ws[lrow][lk + 1] = wsv.y;
        Ws[lrow][lk + 2] = wsv.z;  Ws[lrow][lk + 3] = wsv.w;
        __syncthreads();

        #pragma unroll
        for (int kk = 0; kk < 16; ++kk) {
            float a4[4], wm4[4], ws4[4];
            #pragma unroll
            for (int i = 0; i < 4; ++i) a4[i] = Ash[ty * 4 + i][kk];
            #pragma unroll
            for (int jj = 0; jj < 4; ++jj) wm4[jj] = Wm[tx * 4 + jj][kk];
            #pragma unroll
            for (int jj = 0; jj < 4; ++jj) ws4[jj] = Ws[tx * 4 + jj][kk];
            #pragma unroll
            for (int i = 0; i < 4; ++i)
                #pragma unroll
                for (int jj = 0; jj < 4; ++jj) {
                    accm[i][jj] += a4[i] * wm4[jj];
                    accs[i][jj] += a4[i] * ws4[jj];
                }
        }
    }

    float4 bm = *reinterpret_cast<const float4*>(&bmu[tx * 4]);
    float4 bs = *reinterpret_cast<const float4*>(&bstd[tx * 4]);
    #pragma unroll
    for (int i = 0; i < 4; ++i) {
        const size_t m = (size_t)(m0 + ty * 4 + i);
        float4 om, os;
        om.x = accm[i][0] + bm.x;  om.y = accm[i][1] + bm.y;
        om.z = accm[i][2] + bm.z;  om.w = accm[i][3] + bm.w;
        os.x = accs[i][0] + bs.x;  os.y = accs[i][1] + bs.y;
        os.z = accs[i][2] + bs.z;  os.w = accs[i][3] + bs.w;
        *reinterpret_cast<float4*>(&pre_mu[m * Z_ + tx * 4])  = om;
        *reinterpret_cast<float4*>(&pre_std[m * Z_ + tx * 4]) = os;
    }
}

// ---------------------------------------------------------------------------
// Kernel 2: the recurrence. TWO independent batch rows per wave (rows b and
// b+64) sharing the SAME weight registers (weights are batch-invariant).
//
// R6 lesson: single-chain-per-wave is latency-bound (1090 cy/step, only
// ~15% issue): the LDS broadcast round trip + dot chains + softplus all
// serialize with nothing to fill the stalls. Interleaving a second
// independent chain fills them at the cost of ~36 extra VGPRs — per-row
// step cost should drop ~1.7x. Weights stay packed f16 (64 VGPRs,
// v_dot2_f32_f16), z broadcast per row via its own f16 LDS buffer with
// same-address b64 reads (HW broadcast). Single wave -> no barrier, only
// a wave-internal lgkmcnt(0) (R1 lesson: never __syncthreads here).
// ---------------------------------------------------------------------------
__global__ __launch_bounds__(64)
__attribute__((amdgpu_waves_per_eu(1, 1)))
void recurrent_kernel(
    const float* __restrict__ pre_mu,   // [M_, 64]
    const float* __restrict__ pre_std,  // [M_, 64]
    const float* __restrict__ eps,      // [B_, T_, 64]
    const float* __restrict__ Wmu,      // [64, 320]
    const float* __restrict__ Wstd,     // [64, 320]
    float* __restrict__ out)            // z | mu | std, each [B_, T_, 64]
{
    const int b = blockIdx.x;           // 0..63
    const int j = threadIdx.x;

    // recurrent weights as packed f16 pairs: 64 VGPRs total, shared by rows.
    h2 wmuh[32], wstdh[32];
    {
        const float4* wm4 = reinterpret_cast<const float4*>(&Wmu[(size_t)j * 320 + 256]);
        const float4* ws4 = reinterpret_cast<const float4*>(&Wstd[(size_t)j * 320 + 256]);
        #pragma unroll
        for (int k = 0; k < 16; ++k) {
            const float4 a = wm4[k];
            const float4 s = ws4[k];
            wmuh[2 * k + 0] = (h2){(_Float16)a.x, (_Float16)a.y};
            wmuh[2 * k + 1] = (h2){(_Float16)a.z, (_Float16)a.w};
            wstdh[2 * k + 0] = (h2){(_Float16)s.x, (_Float16)s.y};
            wstdh[2 * k + 1] = (h2){(_Float16)s.z, (_Float16)s.w};
        }
        #pragma unroll
        for (int k = 0; k < 32; ++k) {
            asm volatile("" : "+v"(wmuh[k]));
            asm volatile("" : "+v"(wstdh[k]));
        }
    }

    __shared__ __align__(16) _Float16 zsA[2][64];
    __shared__ __align__(16) _Float16 zsB[2][64];

    const size_t baseA = (size_t)b * T_ * Z_;
    const size_t baseB = (size_t)(b + 64) * T_ * Z_;
    float* __restrict__ zo   = out;
    float* __restrict__ muo  = out + (size_t)M_ * Z_;
    float* __restrict__ stdo = out + (size_t)2 * M_ * Z_;

    // prefetch t = 0, 1 for both rows
    float pmA0 = pre_mu[baseA + j], psA0 = pre_std[baseA + j], evA0 = eps[baseA + j];
    float pmB0 = pre_mu[baseB + j], psB0 = pre_std[baseB + j], evB0 = eps[baseB + j];
    float pmA1 = pre_mu[baseA + Z_ + j], psA1 = pre_std[baseA + Z_ + j], evA1 = eps[baseA + Z_ + j];
    float pmB1 = pre_mu[baseB + Z_ + j], psB1 = pre_std[baseB + Z_ + j], evB1 = eps[baseB + Z_ + j];

    // z_{-1} = 0 published to buffer 0
    zsA[0][j] = (_Float16)0.0f;
    zsB[0][j] = (_Float16)0.0f;

    for (int t = 0; t < T_; ++t) {
        // make last iteration's z-writes (and prologue writes) visible
        asm volatile("s_waitcnt lgkmcnt(0)" ::: "memory");

        // prefetch t+2 for both rows (2 iterations of slack > HBM latency)
        float pmA2 = 0.f, psA2 = 0.f, evA2 = 0.f;
        float pmB2 = 0.f, psB2 = 0.f, evB2 = 0.f;
        if (t + 2 < T_) {
            const size_t ia = baseA + (size_t)(t + 2) * Z_ + j;
            const size_t ib = baseB + (size_t)(t + 2) * Z_ + j;
            pmA2 = pre_mu[ia];  psA2 = pre_std[ia];  evA2 = eps[ia];
            pmB2 = pre_mu[ib];  psB2 = pre_std[ib];  evB2 = eps[ib];
        }

        // two interleaved f16 matvecs; broadcast reads from the two buffers.
        const h4* __restrict__ z4A = reinterpret_cast<const h4*>(zsA[t & 1]);
        const h4* __restrict__ z4B = reinterpret_cast<const h4*>(zsB[t & 1]);
        float amA[4] = {pmA0, 0.f, 0.f, 0.f}, asA[4] = {psA0, 0.f, 0.f, 0.f};
        float amB[4] = {pmB0, 0.f, 0.f, 0.f}, asB[4] = {psB0, 0.f, 0.f, 0.f};
        #pragma unroll
        for (int k = 0; k < 16; ++k) {
            const h4 qA = z4A[k];
            const h4 qB = z4B[k];
            const h2 loA = __builtin_shufflevector(qA, qA, 0, 1);
            const h2 hiA = __builtin_shufflevector(qA, qA, 2, 3);
            const h2 loB = __builtin_shufflevector(qB, qB, 0, 1);
            const h2 hiB = __builtin_shufflevector(qB, qB, 2, 3);
            const int a = k & 3;
            amA[a] = __builtin_amdgcn_fdot2(loA, wmuh[2 * k + 0], amA[a], false);
            amB[a] = __builtin_amdgcn_fdot2(loB, wmuh[2 * k + 0], amB[a], false);
            asA[a] = __builtin_amdgcn_fdot2(loA, wstdh[2 * k + 0], asA[a], false);
            asB[a] = __builtin_amdgcn_fdot2(loB, wstdh[2 * k + 0], asB[a], false);
            amA[a] = __builtin_amdgcn_fdot2(hiA, wmuh[2 * k + 1], amA[a], false);
            amB[a] = __builtin_amdgcn_fdot2(hiB, wmuh[2 * k + 1], amB[a], false);
            asA[a] = __builtin_amdgcn_fdot2(hiA, wstdh[2 * k + 1], asA[a], false);
            asB[a] = __builtin_amdgcn_fdot2(hiB, wstdh[2 * k + 1], asB[a], false);
        }
        const float muA = (amA[0] + amA[1]) + (amA[2] + amA[3]);
        const float sxA = (asA[0] + asA[1]) + (asA[2] + asA[3]);
        const float muB = (amB[0] + amB[1]) + (amB[2] + amB[3]);
        const float sxB = (asB[0] + asB[1]) + (asB[2] + asB[3]);
        const float spA = (sxA > 20.0f) ? sxA : __logf(1.0f + __expf(sxA));
        const float spB = (sxB > 20.0f) ? sxB : __logf(1.0f + __expf(sxB));
        const float sdA = spA + 1e-4f;
        const float sdB = spB + 1e-4f;
        const float zA = muA + evA0 * sdA;
        const float zB = muB + evB0 * sdB;

        // publish z_t for step t+1 immediately (gets a head start on the
        // write latency while the global stores below are being issued)
        zsA[(t + 1) & 1][j] = (_Float16)zA;
        zsB[(t + 1) & 1][j] = (_Float16)zB;

        const size_t oA = baseA + (size_t)t * Z_ + j;
        const size_t oB = baseB + (size_t)t * Z_ + j;
        zo[oA]   = zA;   zo[oB]   = zB;
        muo[oA]  = muA;  muo[oB]  = muB;
        stdo[oA] = sdA;  stdo[oB] = sdB;

        pmA0 = pmA1; psA0 = psA1; evA0 = evA1;
        pmB0 = pmB1; psB0 = psB1; evB0 = evB1;
        pmA1 = pmA2; psA1 = psA2; evA1 = evA2;
        pmB1 = pmB2; psB1 = psB2; evB1 = evB2;
    }
}

extern "C" void kernel_launch(void* const* d_in, const int* in_sizes, int n_in,
                              void* d_out, int out_size, void* d_ws, size_t ws_size,
                              hipStream_t stream) {
    const float* input_q = (const float*)d_in[0];  // [B, T, H]
    const float* eps     = (const float*)d_in[1];  // [B, T, Z]
    const float* W_mu    = (const float*)d_in[2];  // [Z, H+Z]
    const float* b_mu    = (const float*)d_in[3];  // [Z]
    const float* W_std   = (const float*)d_in[4];  // [Z, H+Z]
    const float* b_std   = (const float*)d_in[5];  // [Z]
    float* out = (float*)d_out;

    float* pre_mu  = (float*)d_ws;                      // [M_, 64]
    float* pre_std = pre_mu + (size_t)M_ * Z_;          // [M_, 64]

    precompute_kernel<<<M_ / 64, 256, 0, stream>>>(
        input_q, W_mu, W_std, b_mu, b_std, pre_mu, pre_std);

    recurrent_kernel<<<B_ / 2, 64, 0, stream>>>(
        pre_mu, pre_std, eps, W_mu, W_std, out);
}